// Round 3
// baseline (233.821 us; speedup 1.0000x reference)
//
#include <hip/hip_runtime.h>

// out[b, n, k, :] = features[b, topk_indices[b, n, k], :]
// B=32, N=4096, K=20, F=64, fp32.
// Write-BW-bound: 671 MB out (streamed once -> nontemporal), 33.5 MB features
// (re-read K=20x -> keep cacheable in L2), 10.5 MB idx (streamed -> nontemporal).

typedef float floatx4 __attribute__((ext_vector_type(4)));  // native vec: OK for nontemporal builtins

constexpr int B = 32, N = 4096, K = 20, F = 64;
constexpr unsigned TOTAL_ROWS = (unsigned)B * N * K;          // 2,621,440
constexpr unsigned VEC_PER_ROW = F / 4;                       // 16 float4 per row
constexpr unsigned TOTAL_VEC = TOTAL_ROWS * VEC_PER_ROW;      // 41,943,040
constexpr unsigned NK = (unsigned)N * K;                      // 81,920

constexpr unsigned BLOCK = 256;
constexpr unsigned GRID = 2048;
constexpr unsigned THREADS = GRID * BLOCK;                    // 524,288
constexpr unsigned ITERS = TOTAL_VEC / THREADS;               // exactly 80
static_assert(ITERS * THREADS == TOTAL_VEC, "exact tiling");

__global__ __launch_bounds__(BLOCK) void gather_rows_kernel(
    const int* __restrict__ idx,      // [B, N, K]
    const float* __restrict__ feat,   // [B, N, F]
    float* __restrict__ out)          // [B, N, K, F]
{
    unsigned i = blockIdx.x * BLOCK + threadIdx.x;
    const floatx4* __restrict__ featv = reinterpret_cast<const floatx4*>(feat);
    floatx4* __restrict__ outv = reinterpret_cast<floatx4*>(out);

#pragma unroll 4
    for (unsigned j = 0; j < ITERS; ++j, i += THREADS) {
        unsigned row = i >> 4;          // output row in [0, B*N*K)
        unsigned v   = i & 15u;         // float4 slot within the row
        unsigned b   = row / NK;        // batch (magic multiply)
        int id = __builtin_nontemporal_load(&idx[row]);   // streamed once
        unsigned src = (b * (unsigned)N + (unsigned)id) * VEC_PER_ROW + v;
        floatx4 val = featv[src];       // cacheable: keep features in L2
        __builtin_nontemporal_store(val, &outv[i]);       // don't pollute L2
    }
}

extern "C" void kernel_launch(void* const* d_in, const int* in_sizes, int n_in,
                              void* d_out, int out_size, void* d_ws, size_t ws_size,
                              hipStream_t stream) {
    const int*   idx  = (const int*)d_in[0];    // topk_indices [B,N,K] int32
    const float* feat = (const float*)d_in[1];  // features [B,N,F] fp32
    float*       out  = (float*)d_out;          // [B,N,K,F] fp32

    gather_rows_kernel<<<GRID, BLOCK, 0, stream>>>(idx, feat, out);
}